// Round 1
// baseline (137.885 us; speedup 1.0000x reference)
//
#include <hip/hip_runtime.h>

// Problem constants (match reference)
#define BB 32
#define SS 64
#define TT 512
#define VV 50257
#define DD 128

// Kernel 1: prev[b,t] = nearest t' < t with same token, else -1.
// One block per batch row; row staged in LDS; backward scan with early exit.
__global__ __launch_bounds__(TT) void prev_kernel(const int* __restrict__ tok,
                                                  int* __restrict__ prev) {
    const int b = blockIdx.x;
    const int t = threadIdx.x;
    __shared__ int row[TT];
    row[t] = tok[b * TT + t];
    __syncthreads();
    const int v = row[t];
    int p = -1;
    for (int u = t - 1; u >= 0; --u) {
        if (row[u] == v) { p = u; break; }
    }
    prev[b * TT + t] = p;
}

// Kernel 2: one block per (b,s) span. 256 threads = 8 position-groups x 32 lanes.
// Each lane owns 4 consecutive d's (float4). Group g walks positions g, g+8, ...
// accumulating W rows of first-occurrence tokens; tree-reduce the 8 partials.
__global__ __launch_bounds__(256) void bow_kernel(const int* __restrict__ tok,
                                                  const int* __restrict__ prev,
                                                  const int* __restrict__ spans,
                                                  const float* __restrict__ W,
                                                  const float* __restrict__ bias,
                                                  float* __restrict__ out) {
    const int bs  = blockIdx.x;      // b*S + s
    const int b   = bs >> 6;         // S = 64
    const int tid = threadIdx.x;

    const int i = spans[bs * 2 + 0];
    const int j = spans[bs * 2 + 1];
    const int L = j - i;

    // Stage span tokens in LDS; fold the dedup predicate in (-1 = skip).
    __shared__ int tokS[TT];
    for (int t = i + tid; t < j; t += 256) {
        const int idx = b * TT + t;
        const int v = tok[idx];
        tokS[t - i] = (prev[idx] >= i) ? -1 : v;
    }
    __syncthreads();

    const int lane = tid & 31;   // 0..31 -> d = lane*4 .. lane*4+3
    const int g    = tid >> 5;   // 0..7  -> position group

    float4 acc = make_float4(0.f, 0.f, 0.f, 0.f);
    for (int k = g; k < L; k += 8) {
        const int v = tokS[k];
        if (v >= 0) {
            const float4 w = *reinterpret_cast<const float4*>(
                W + (size_t)v * DD + lane * 4);
            acc.x += w.x; acc.y += w.y; acc.z += w.z; acc.w += w.w;
        }
    }

    // Reduce the 8 position-group partials.
    __shared__ float4 red[256];
    red[tid] = acc;
    __syncthreads();
    for (int s4 = 4; s4 > 0; s4 >>= 1) {
        if (g < s4) {
            float4 o = red[tid + (s4 << 5)];
            float4 m = red[tid];
            m.x += o.x; m.y += o.y; m.z += o.z; m.w += o.w;
            red[tid] = m;
        }
        __syncthreads();
    }

    if (g == 0) {
        float4 r = red[tid];
        const float4 bb = *reinterpret_cast<const float4*>(bias + lane * 4);
        r.x += bb.x; r.y += bb.y; r.z += bb.z; r.w += bb.w;
        reinterpret_cast<float4*>(out)[bs * 32 + lane] = r;
    }
}

extern "C" void kernel_launch(void* const* d_in, const int* in_sizes, int n_in,
                              void* d_out, int out_size, void* d_ws, size_t ws_size,
                              hipStream_t stream) {
    const int*   word_encs = (const int*)  d_in[0];   // (B,T) int32
    const int*   span_idxs = (const int*)  d_in[1];   // (B,S,2) int32
    const float* W         = (const float*)d_in[2];   // (V,D) f32
    const float* bias      = (const float*)d_in[3];   // (D,) f32
    float*       out       = (float*)      d_out;     // (B,S,D) f32

    int* prev = (int*)d_ws;                            // B*T ints = 64 KB

    prev_kernel<<<BB, TT, 0, stream>>>(word_encs, prev);
    bow_kernel<<<BB * SS, 256, 0, stream>>>(word_encs, prev, span_idxs, W, bias, out);
}